// Round 1
// baseline (17751.900 us; speedup 1.0000x reference)
//
#include <hip/hip_runtime.h>

#define DEV __device__ __forceinline__

using bf16x8 = __attribute__((ext_vector_type(8))) short;
using f32x4  = __attribute__((ext_vector_type(4))) float;

constexpr int B_ = 64, S_ = 512, V_ = 32000, E_ = 512, H_ = 1024, C_ = 1024;
constexpr int NWG = 128;   // scan workgroups (each owns JS columns of H)
constexpr int JS  = 8;

// ---------------- workspace layout (bytes) ----------------
constexpr size_t OFF_FLAGS = 0;                                   // 256 B (barrier counter)
constexpr size_t OFF_BIASG = 256;                                 // 3072 f32 (bz|br|bu folded)
constexpr size_t OFF_BCOMB = OFF_BIASG + 3072*4;                  // 1024 f32
constexpr size_t OFF_HB    = OFF_BCOMB + 1024*4;                  // h bf16 [64][1024]
constexpr size_t OFF_RHB   = OFF_HB + (size_t)B_*H_*2;            // r*h bf16 [64][1024]
constexpr size_t OFF_WCOMB = OFF_RHB + (size_t)B_*H_*2;           // [1024][1024] bf16
constexpr size_t OFF_WXALL = OFF_WCOMB + (size_t)C_*H_*2;         // [3072][512] bf16
constexpr size_t OFF_WZRF  = OFF_WXALL + (size_t)3072*512*2;      // stage1 frags 128*32KB
constexpr size_t OFF_WUF   = OFF_WZRF + (size_t)NWG*32768;        // stage2 frags 128*32KB
constexpr size_t OFF_EMB   = OFF_WUF + (size_t)NWG*32768;         // embed bf16 [32000][512]
constexpr size_t OFF_G     = OFF_EMB + (size_t)V_*E_*2;           // [512][64][3072] bf16
constexpr size_t OFF_HS    = OFF_G + (size_t)S_*B_*3072*2;        // [512][64][1024] bf16
constexpr size_t WS_NEED   = OFF_HS + (size_t)S_*B_*H_*2;         // ~301 MiB

DEV unsigned short f2bf(float f){
  unsigned int x; __builtin_memcpy(&x, &f, 4);
  x += 0x7fffu + ((x>>16)&1u);
  return (unsigned short)(x>>16);
}
DEV float bf2f(unsigned short u){
  unsigned int x = ((unsigned int)u)<<16; float f; __builtin_memcpy(&f,&x,4); return f;
}

// ---------------- prep kernels ----------------
__global__ void k_cvt_embed(const float* __restrict__ src, unsigned short* __restrict__ dst){
  for (int i = blockIdx.x*blockDim.x + threadIdx.x; i < V_*E_; i += gridDim.x*blockDim.x)
    dst[i] = f2bf(src[i]);
}

__global__ void k_build_wx(const float* __restrict__ Wzx, const float* __restrict__ Wrx,
                           const float* __restrict__ Wux, unsigned short* __restrict__ out){
  for (int i = blockIdx.x*blockDim.x + threadIdx.x; i < 3072*512; i += gridDim.x*blockDim.x){
    int n = i>>9, k = i&511;
    int g = n>>10, r = n&1023;
    const float* W = (g==0) ? Wzx : (g==1) ? Wrx : Wux;
    out[i] = f2bf(W[(size_t)r*512 + k]);
  }
}

__global__ void k_biasg(const float* bzh, const float* bzx, const float* brh, const float* brx,
                        const float* buh, const float* bux, float* __restrict__ out){
  for (int i = blockIdx.x*blockDim.x + threadIdx.x; i < 3072; i += gridDim.x*blockDim.x){
    int g = i>>10, r = i&1023;
    float v = (g==0) ? (bzh[r]+bzx[r]) : (g==1) ? (brh[r]+brx[r]) : (buh[r]+bux[r]);
    out[i] = v;
  }
}

// pack recurrent weights into exact MFMA B-fragment order:
// frag[((wg*32 + ck)*64 + lane)*8 + e] = B[k][col], col=lane&15, k=ck*32+(lane>>4)*8+e
// stage1: col<8 -> Wzh row wg*8+col ; col>=8 -> Wrh row wg*8+col-8
// stage2: col<8 -> Wuh row wg*8+col ; col>=8 -> 0
__global__ void k_frag(const float* __restrict__ Wa, const float* __restrict__ Wb,
                       unsigned short* __restrict__ out){
  for (int i = blockIdx.x*blockDim.x + threadIdx.x; i < NWG*32*64*8; i += gridDim.x*blockDim.x){
    int e  = i & 7;
    int l  = (i>>3) & 63;
    int ck = (i>>9) & 31;
    int wg = i>>14;
    int j  = l & 15;
    int k  = ck*32 + ((l>>4)<<3) + e;
    int row = wg*JS + (j&7);
    float v;
    if (j < 8) v = Wa[(size_t)row*H_ + k];
    else       v = Wb ? Wb[(size_t)row*H_ + k] : 0.0f;
    out[i] = f2bf(v);
  }
}

// Wcomb[c][h] = sum_x Wc[c][x] * Wxh[x][h]   ([1024x512]@[512x1024])
__global__ __launch_bounds__(256) void k_wcomb(const float* __restrict__ Wc,
                                               const float* __restrict__ Wxh,
                                               unsigned short* __restrict__ Wcomb){
  __shared__ float wc[16][512];
  const int c0 = blockIdx.x*16;
  const int tid = threadIdx.x;
  for (int q = tid; q < 16*512; q += 256)
    wc[q>>9][q&511] = Wc[(size_t)(c0 + (q>>9))*512 + (q&511)];
  __syncthreads();
  const int h4 = tid*4;
  f32x4 acc[16];
  #pragma unroll
  for (int ci=0; ci<16; ++ci) acc[ci] = (f32x4){0.f,0.f,0.f,0.f};
  for (int x=0; x<512; ++x){
    f32x4 wv = *(const f32x4*)(Wxh + (size_t)x*H_ + h4);
    #pragma unroll
    for (int ci=0; ci<16; ++ci) acc[ci] += wc[ci][x] * wv;
  }
  #pragma unroll
  for (int ci=0; ci<16; ++ci)
    #pragma unroll
    for (int e=0; e<4; ++e)
      Wcomb[(size_t)(c0+ci)*H_ + h4 + e] = f2bf(acc[ci][e]);
}

__global__ void k_bcomb(const float* __restrict__ Wc, const float* __restrict__ bxh,
                        const float* __restrict__ bc, float* __restrict__ out){
  int c = blockIdx.x*blockDim.x + threadIdx.x;
  if (c >= C_) return;
  float s = bc[c];
  for (int x=0; x<512; ++x) s += Wc[(size_t)c*512 + x]*bxh[x];
  out[c] = s;
}

__global__ void k_hinit(const float* __restrict__ h0, unsigned short* __restrict__ hb){
  for (int i = blockIdx.x*blockDim.x + threadIdx.x; i < B_*H_; i += gridDim.x*blockDim.x)
    hb[i] = f2bf(h0[i]);
}

// ---------------- tiled bf16 MFMA GEMM (C = A @ Bw^T + bias) ----------------
// A: [M][K] bf16 rows (or gathered embed rows), Bw: [N][K] bf16 rows.
// 128x128 tile, BK=64, 256 threads (2x2 waves of 64x64), reg-staged LDS, XOR-swizzled.
template<bool GATHER, bool SCATTER>
__global__ __launch_bounds__(256) void gemm_bt(
  const unsigned short* __restrict__ Asrc, const int* __restrict__ Xidx,
  const unsigned short* __restrict__ embB,
  const unsigned short* __restrict__ Bw, const float* __restrict__ bias,
  void* __restrict__ Cout, int K, int KT, int NTN, int ldc)
{
  __shared__ unsigned short ldsA[128*64];
  __shared__ unsigned short ldsB[128*64];
  const int bid = blockIdx.x;
  const int tm = bid / NTN, tn = bid % NTN;
  const int m0 = tm*128, n0 = tn*128;
  const int tid = threadIdx.x, wave = tid>>6, lane = tid&63;
  const int wm = (wave&1)*64, wn = (wave>>1)*64;

  const char* srcA[4]; const char* srcB[4];
  int rr[4], cc[4];
  #pragma unroll
  for (int s=0; s<4; ++s){
    int L = s*4096 + tid*16;
    int r = L>>7, cb = L&127;
    rr[s]=r; cc[s]=cb;
    if constexpr (GATHER){
      int m = m0 + r; int tt = m>>6, bb = m&63;
      srcA[s] = (const char*)(embB + (size_t)Xidx[bb*S_ + tt]*(size_t)K);
    } else {
      srcA[s] = (const char*)(Asrc + (size_t)(m0+r)*(size_t)K);
    }
    srcB[s] = (const char*)(Bw + (size_t)(n0+r)*(size_t)K);
  }

  f32x4 acc[4][4];
  #pragma unroll
  for (int a=0;a<4;a++)
    #pragma unroll
    for (int b=0;b<4;b++) acc[a][b] = (f32x4){0.f,0.f,0.f,0.f};

  int4 ra[4], rb[4];
  auto loadRegs = [&](int kt){
    #pragma unroll
    for (int s=0;s<4;s++){
      ra[s] = *(const int4*)(srcA[s] + (size_t)kt*128 + cc[s]);
      rb[s] = *(const int4*)(srcB[s] + (size_t)kt*128 + cc[s]);
    }
  };
  auto writeLDS = [&](){
    #pragma unroll
    for (int s=0;s<4;s++){
      int off = (rr[s]<<7) + (cc[s] ^ ((rr[s]&7)<<4));
      *(int4*)((char*)ldsA + off) = ra[s];
      *(int4*)((char*)ldsB + off) = rb[s];
    }
  };

  loadRegs(0);
  for (int kt=0; kt<KT; ++kt){
    __syncthreads();
    writeLDS();
    if (kt+1 < KT) loadRegs(kt+1);
    __syncthreads();
    #pragma unroll
    for (int ck=0; ck<2; ++ck){
      bf16x8 af[4], bfr[4];
      #pragma unroll
      for (int q=0;q<4;q++){
        int ar = wm + q*16 + (lane&15);
        int ao = (ar<<7) + (((ck<<6) + ((lane>>4)<<4)) ^ ((ar&7)<<4));
        af[q] = *(const bf16x8*)((const char*)ldsA + ao);
        int br = wn + q*16 + (lane&15);
        int bo = (br<<7) + (((ck<<6) + ((lane>>4)<<4)) ^ ((br&7)<<4));
        bfr[q] = *(const bf16x8*)((const char*)ldsB + bo);
      }
      #pragma unroll
      for (int mi=0;mi<4;mi++)
        #pragma unroll
        for (int ni=0;ni<4;ni++)
          acc[mi][ni] = __builtin_amdgcn_mfma_f32_16x16x32_bf16(af[mi], bfr[ni], acc[mi][ni], 0,0,0);
    }
  }

  #pragma unroll
  for (int mi=0;mi<4;mi++){
    #pragma unroll
    for (int ni=0;ni<4;ni++){
      int gm = m0 + wm + mi*16 + ((lane>>4)<<2);
      int gn = n0 + wn + ni*16 + (lane&15);
      float bv = bias[gn];
      #pragma unroll
      for (int r2=0;r2<4;r2++){
        float v = acc[mi][ni][r2] + bv;
        int m = gm + r2;
        if constexpr (SCATTER){
          ((float*)Cout)[ (size_t)((m&63)*S_ + (m>>6))*(size_t)ldc + gn ] = v;
        } else {
          ((unsigned short*)Cout)[ (size_t)m*(size_t)ldc + gn ] = f2bf(v);
        }
      }
    }
  }
}

// ---------------- persistent GRU scan ----------------
DEV bf16x8 ld_frag_coh(const unsigned short* base, int row, int kk){
  const unsigned long long* p = (const unsigned long long*)(base + (size_t)row*H_ + kk);
  unsigned long long q0 = __hip_atomic_load(p,   __ATOMIC_RELAXED, __HIP_MEMORY_SCOPE_AGENT);
  unsigned long long q1 = __hip_atomic_load(p+1, __ATOMIC_RELAXED, __HIP_MEMORY_SCOPE_AGENT);
  union { unsigned long long q[2]; bf16x8 v; } u;
  u.q[0]=q0; u.q[1]=q1; return u.v;
}

DEV void gbar(unsigned int* flag, unsigned int target){
  __syncthreads();
  if (threadIdx.x == 0){
    __hip_atomic_fetch_add(flag, 1u, __ATOMIC_RELEASE, __HIP_MEMORY_SCOPE_AGENT);
    int guard = 0;
    while (__hip_atomic_load(flag, __ATOMIC_RELAXED, __HIP_MEMORY_SCOPE_AGENT) < target){
      __builtin_amdgcn_s_sleep(2);
      if (++guard > (1<<22)) break;   // safety: garbage instead of hang
    }
  }
  __syncthreads();
  asm volatile("" ::: "memory");
}

__global__ __launch_bounds__(256) void k_scan(const float* __restrict__ h0, char* __restrict__ ws){
  const int wg = blockIdx.x;          // 0..127, owns H cols [wg*8, wg*8+8)
  const int tid = threadIdx.x;
  const int wave = tid>>6, lane = tid&63;
  const int j0 = wg*JS;

  unsigned int* flags = (unsigned int*)(ws + OFF_FLAGS);
  unsigned short* hb  = (unsigned short*)(ws + OFF_HB);
  unsigned short* rhb = (unsigned short*)(ws + OFF_RHB);
  const unsigned short* G = (const unsigned short*)(ws + OFF_G);
  unsigned short* Hs  = (unsigned short*)(ws + OFF_HS);
  const char* f1 = ws + OFF_WZRF + (size_t)wg*32768;
  const char* f2 = ws + OFF_WUF  + (size_t)wg*32768;

  const int n  = lane & 15;             // MFMA col
  const int c  = n & 7;                 // column within slice
  const bool isZ = (n < 8);
  const int rbase = (wave<<4) + ((lane>>4)<<2);   // D rows: batch base
  const int arow  = (wave<<4) + n;                // A rows: batch
  const int kkb   = (lane>>4)<<3;

  float h_own[4];                       // fp32 state, valid in isZ lanes
  #pragma unroll
  for (int r2=0;r2<4;r2++)
    h_own[r2] = isZ ? h0[(size_t)(rbase+r2)*H_ + j0 + c] : 0.f;

  for (int t=0; t<S_; ++t){
    // -------- stage 1: z,r = sigmoid(h@Wzr^T + G) --------
    f32x4 a0 = (f32x4){0,0,0,0}, a1 = (f32x4){0,0,0,0};
    #pragma unroll 4
    for (int ck=0; ck<32; ck+=2){
      bf16x8 av0 = ld_frag_coh(hb, arow, ck*32 + kkb);
      bf16x8 bv0 = *(const bf16x8*)(f1 + ((ck*64 + lane)<<4));
      a0 = __builtin_amdgcn_mfma_f32_16x16x32_bf16(av0, bv0, a0, 0,0,0);
      bf16x8 av1 = ld_frag_coh(hb, arow, (ck+1)*32 + kkb);
      bf16x8 bv1 = *(const bf16x8*)(f1 + (((ck+1)*64 + lane)<<4));
      a1 = __builtin_amdgcn_mfma_f32_16x16x32_bf16(av1, bv1, a1, 0,0,0);
    }
    f32x4 accs = a0 + a1;

    float zval[4];
    const int gcol = ((n>>3)<<10) + j0 + c;   // gate0 (z) / gate1 (r) column in G
    #pragma unroll
    for (int r2=0;r2<4;r2++){
      int brow = rbase + r2;
      float g = bf2f(G[(size_t)((t<<6)+brow)*3072 + gcol]);
      float pre = accs[r2] + g;
      float sv = 1.f/(1.f + __expf(-pre));
      float hc = __shfl(h_own[r2], (lane & 48) | c, 64);
      zval[r2] = sv;
      if (!isZ){
        unsigned int mybits = (unsigned int)f2bf(sv*hc);
        unsigned int ob = __shfl_xor(mybits, 1, 64);
        if ((lane&1)==0){
          unsigned int w = mybits | (ob<<16);
          __hip_atomic_store((unsigned int*)(rhb + (size_t)brow*H_ + j0 + c), w,
                             __ATOMIC_RELAXED, __HIP_MEMORY_SCOPE_AGENT);
        }
      }
    }
    gbar(flags, (unsigned)(NWG*(2*t+1)));

    // -------- stage 2: u = tanh((r*h)@Wu^T + G), h' = h + z*(u-h) --------
    f32x4 b0 = (f32x4){0,0,0,0}, b1 = (f32x4){0,0,0,0};
    #pragma unroll 4
    for (int ck=0; ck<32; ck+=2){
      bf16x8 av0 = ld_frag_coh(rhb, arow, ck*32 + kkb);
      bf16x8 bv0 = *(const bf16x8*)(f2 + ((ck*64 + lane)<<4));
      b0 = __builtin_amdgcn_mfma_f32_16x16x32_bf16(av0, bv0, b0, 0,0,0);
      bf16x8 av1 = ld_frag_coh(rhb, arow, (ck+1)*32 + kkb);
      bf16x8 bv1 = *(const bf16x8*)(f2 + (((ck+1)*64 + lane)<<4));
      b1 = __builtin_amdgcn_mfma_f32_16x16x32_bf16(av1, bv1, b1, 0,0,0);
    }
    f32x4 acc2 = b0 + b1;

    if (isZ){
      #pragma unroll
      for (int r2=0;r2<4;r2++){
        int brow = rbase + r2;
        float g = bf2f(G[(size_t)((t<<6)+brow)*3072 + 2048 + j0 + c]);
        float up = acc2[r2] + g;
        float e  = __expf(-2.f*up);
        float u  = (1.f - e)/(1.f + e);
        float hn = h_own[r2] + zval[r2]*(u - h_own[r2]);
        h_own[r2] = hn;
        unsigned short hbf = f2bf(hn);
        Hs[(size_t)((t<<6)+brow)*H_ + j0 + c] = hbf;          // plain store (read post-kernel)
        unsigned int ob = __shfl_xor((unsigned int)hbf, 1, 64);
        if ((lane&1)==0){
          unsigned int w = ((unsigned int)hbf) | (ob<<16);
          __hip_atomic_store((unsigned int*)(hb + (size_t)brow*H_ + j0 + c), w,
                             __ATOMIC_RELAXED, __HIP_MEMORY_SCOPE_AGENT);
        }
      }
    }
    gbar(flags, (unsigned)(NWG*(2*t+2)));
  }
}

// ---------------- launch ----------------
extern "C" void kernel_launch(void* const* d_in, const int* in_sizes, int n_in,
                              void* d_out, int out_size, void* d_ws, size_t ws_size,
                              hipStream_t stream)
{
  const int*   X    = (const int*)  d_in[0];
  const float* h0   = (const float*)d_in[1];
  const float* emb  = (const float*)d_in[2];
  const float* Wzh  = (const float*)d_in[3];
  const float* bzh  = (const float*)d_in[4];
  const float* Wzx  = (const float*)d_in[5];
  const float* bzx  = (const float*)d_in[6];
  const float* Wrh  = (const float*)d_in[7];
  const float* brh  = (const float*)d_in[8];
  const float* Wrx  = (const float*)d_in[9];
  const float* brx  = (const float*)d_in[10];
  const float* Wuh  = (const float*)d_in[11];
  const float* buh  = (const float*)d_in[12];
  const float* Wux  = (const float*)d_in[13];
  const float* bux  = (const float*)d_in[14];
  const float* Wxh  = (const float*)d_in[15];
  const float* bxh  = (const float*)d_in[16];
  const float* Wc   = (const float*)d_in[17];
  const float* bc   = (const float*)d_in[18];
  (void)in_sizes; (void)n_in;

  char* ws = (char*)d_ws;
  if (ws_size < WS_NEED){
    hipMemsetAsync(d_out, 0, (size_t)out_size*4, stream);  // visible failure
    return;
  }

  hipMemsetAsync(ws + OFF_FLAGS, 0, 256, stream);

  k_cvt_embed<<<4096, 256, 0, stream>>>(emb, (unsigned short*)(ws + OFF_EMB));
  k_build_wx <<<1536, 256, 0, stream>>>(Wzx, Wrx, Wux, (unsigned short*)(ws + OFF_WXALL));
  k_biasg    <<<12,   256, 0, stream>>>(bzh, bzx, brh, brx, buh, bux, (float*)(ws + OFF_BIASG));
  k_frag     <<<2048, 256, 0, stream>>>(Wzh, Wrh,    (unsigned short*)(ws + OFF_WZRF));
  k_frag     <<<2048, 256, 0, stream>>>(Wuh, nullptr,(unsigned short*)(ws + OFF_WUF));
  k_wcomb    <<<64,   256, 0, stream>>>(Wc, Wxh, (unsigned short*)(ws + OFF_WCOMB));
  k_bcomb    <<<4,    256, 0, stream>>>(Wc, bxh, bc, (float*)(ws + OFF_BCOMB));
  k_hinit    <<<64,   256, 0, stream>>>(h0, (unsigned short*)(ws + OFF_HB));

  // G = gather(embed) @ WxAll^T + bias  -> [S*B rows (t-major), 3072] bf16
  gemm_bt<true,false><<<6144, 256, 0, stream>>>(
      nullptr, X, (const unsigned short*)(ws + OFF_EMB),
      (const unsigned short*)(ws + OFF_WXALL), (const float*)(ws + OFF_BIASG),
      (void*)(ws + OFF_G), 512, 8, 24, 3072);

  k_scan<<<NWG, 256, 0, stream>>>(h0, ws);

  // out[b,t,c] = Hs @ Wcomb^T + bcomb (scatter rows t*64+b -> b*512+t)
  gemm_bt<false,true><<<2048, 256, 0, stream>>>(
      (const unsigned short*)(ws + OFF_HS), nullptr, nullptr,
      (const unsigned short*)(ws + OFF_WCOMB), (const float*)(ws + OFF_BCOMB),
      d_out, 1024, 16, 8, 1024);
}

// Round 2
// 12346.275 us; speedup vs baseline: 1.4378x; 1.4378x over previous
//
#include <hip/hip_runtime.h>

#define DEV __device__ __forceinline__

using bf16x8 = __attribute__((ext_vector_type(8))) short;
using f32x4  = __attribute__((ext_vector_type(4))) float;

constexpr int B_ = 64, S_ = 512, V_ = 32000, E_ = 512, H_ = 1024, C_ = 1024;
constexpr int NWG = 128;   // scan workgroups (each owns JS columns of H)
constexpr int JS  = 8;

// ---------------- workspace layout (bytes) ----------------
constexpr size_t OFF_FH    = 0;                                   // 128 u32 h-ready flags
constexpr size_t OFF_FR    = 512;                                 // 128 u32 rh-ready flags
constexpr size_t OFF_BIASG = 1024;                                // 3072 f32 (bz|br|bu folded)
constexpr size_t OFF_BCOMB = OFF_BIASG + 3072*4;                  // 1024 f32
constexpr size_t OFF_HB    = OFF_BCOMB + 1024*4;                  // h bf16 [64][1024]
constexpr size_t OFF_RHB   = OFF_HB + (size_t)B_*H_*2;            // r*h bf16 [64][1024]
constexpr size_t OFF_WCOMB = OFF_RHB + (size_t)B_*H_*2;           // [1024][1024] bf16
constexpr size_t OFF_WXALL = OFF_WCOMB + (size_t)C_*H_*2;         // [3072][512] bf16
constexpr size_t OFF_WZRF  = OFF_WXALL + (size_t)3072*512*2;      // stage1 frags 128*32KB
constexpr size_t OFF_WUF   = OFF_WZRF + (size_t)NWG*32768;        // stage2 frags 128*32KB
constexpr size_t OFF_EMB   = OFF_WUF + (size_t)NWG*32768;         // embed bf16 [32000][512]
constexpr size_t OFF_G     = OFF_EMB + (size_t)V_*E_*2;           // [512][64][3072] bf16
constexpr size_t OFF_HS    = OFF_G + (size_t)S_*B_*3072*2;        // [512][64][1024] bf16
constexpr size_t WS_NEED   = OFF_HS + (size_t)S_*B_*H_*2;         // ~301 MiB

DEV unsigned short f2bf(float f){
  unsigned int x; __builtin_memcpy(&x, &f, 4);
  x += 0x7fffu + ((x>>16)&1u);
  return (unsigned short)(x>>16);
}
DEV float bf2f(unsigned short u){
  unsigned int x = ((unsigned int)u)<<16; float f; __builtin_memcpy(&f,&x,4); return f;
}

// ---------------- prep kernels ----------------
__global__ void k_cvt_embed(const float* __restrict__ src, unsigned short* __restrict__ dst){
  for (int i = blockIdx.x*blockDim.x + threadIdx.x; i < V_*E_; i += gridDim.x*blockDim.x)
    dst[i] = f2bf(src[i]);
}

__global__ void k_build_wx(const float* __restrict__ Wzx, const float* __restrict__ Wrx,
                           const float* __restrict__ Wux, unsigned short* __restrict__ out){
  for (int i = blockIdx.x*blockDim.x + threadIdx.x; i < 3072*512; i += gridDim.x*blockDim.x){
    int n = i>>9, k = i&511;
    int g = n>>10, r = n&1023;
    const float* W = (g==0) ? Wzx : (g==1) ? Wrx : Wux;
    out[i] = f2bf(W[(size_t)r*512 + k]);
  }
}

__global__ void k_biasg(const float* bzh, const float* bzx, const float* brh, const float* brx,
                        const float* buh, const float* bux, float* __restrict__ out){
  for (int i = blockIdx.x*blockDim.x + threadIdx.x; i < 3072; i += gridDim.x*blockDim.x){
    int g = i>>10, r = i&1023;
    float v = (g==0) ? (bzh[r]+bzx[r]) : (g==1) ? (brh[r]+brx[r]) : (buh[r]+bux[r]);
    out[i] = v;
  }
}

// pack recurrent weights into exact MFMA B-fragment order:
// frag[((wg*32 + ck)*64 + lane)*8 + e] = B[k][col], col=lane&15, k=ck*32+(lane>>4)*8+e
// stage1: col<8 -> Wzh row wg*8+col ; col>=8 -> Wrh row wg*8+col-8
// stage2: col<8 -> Wuh row wg*8+col ; col>=8 -> 0
__global__ void k_frag(const float* __restrict__ Wa, const float* __restrict__ Wb,
                       unsigned short* __restrict__ out){
  for (int i = blockIdx.x*blockDim.x + threadIdx.x; i < NWG*32*64*8; i += gridDim.x*blockDim.x){
    int e  = i & 7;
    int l  = (i>>3) & 63;
    int ck = (i>>9) & 31;
    int wg = i>>14;
    int j  = l & 15;
    int k  = ck*32 + ((l>>4)<<3) + e;
    int row = wg*JS + (j&7);
    float v;
    if (j < 8) v = Wa[(size_t)row*H_ + k];
    else       v = Wb ? Wb[(size_t)row*H_ + k] : 0.0f;
    out[i] = f2bf(v);
  }
}

// Wcomb[c][h] = sum_x Wc[c][x] * Wxh[x][h]   ([1024x512]@[512x1024])
__global__ __launch_bounds__(256) void k_wcomb(const float* __restrict__ Wc,
                                               const float* __restrict__ Wxh,
                                               unsigned short* __restrict__ Wcomb){
  __shared__ float wc[16][512];
  const int c0 = blockIdx.x*16;
  const int tid = threadIdx.x;
  for (int q = tid; q < 16*512; q += 256)
    wc[q>>9][q&511] = Wc[(size_t)(c0 + (q>>9))*512 + (q&511)];
  __syncthreads();
  const int h4 = tid*4;
  f32x4 acc[16];
  #pragma unroll
  for (int ci=0; ci<16; ++ci) acc[ci] = (f32x4){0.f,0.f,0.f,0.f};
  for (int x=0; x<512; ++x){
    f32x4 wv = *(const f32x4*)(Wxh + (size_t)x*H_ + h4);
    #pragma unroll
    for (int ci=0; ci<16; ++ci) acc[ci] += wc[ci][x] * wv;
  }
  #pragma unroll
  for (int ci=0; ci<16; ++ci)
    #pragma unroll
    for (int e=0; e<4; ++e)
      Wcomb[(size_t)(c0+ci)*H_ + h4 + e] = f2bf(acc[ci][e]);
}

__global__ void k_bcomb(const float* __restrict__ Wc, const float* __restrict__ bxh,
                        const float* __restrict__ bc, float* __restrict__ out){
  int c = blockIdx.x*blockDim.x + threadIdx.x;
  if (c >= C_) return;
  float s = bc[c];
  for (int x=0; x<512; ++x) s += Wc[(size_t)c*512 + x]*bxh[x];
  out[c] = s;
}

__global__ void k_hinit(const float* __restrict__ h0, unsigned short* __restrict__ hb){
  for (int i = blockIdx.x*blockDim.x + threadIdx.x; i < B_*H_; i += gridDim.x*blockDim.x)
    hb[i] = f2bf(h0[i]);
}

// ---------------- tiled bf16 MFMA GEMM (C = A @ Bw^T + bias) ----------------
template<bool GATHER, bool SCATTER>
__global__ __launch_bounds__(256) void gemm_bt(
  const unsigned short* __restrict__ Asrc, const int* __restrict__ Xidx,
  const unsigned short* __restrict__ embB,
  const unsigned short* __restrict__ Bw, const float* __restrict__ bias,
  void* __restrict__ Cout, int K, int KT, int NTN, int ldc)
{
  __shared__ unsigned short ldsA[128*64];
  __shared__ unsigned short ldsB[128*64];
  const int bid = blockIdx.x;
  const int tm = bid / NTN, tn = bid % NTN;
  const int m0 = tm*128, n0 = tn*128;
  const int tid = threadIdx.x, wave = tid>>6, lane = tid&63;
  const int wm = (wave&1)*64, wn = (wave>>1)*64;

  const char* srcA[4]; const char* srcB[4];
  int rr[4], cc[4];
  #pragma unroll
  for (int s=0; s<4; ++s){
    int L = s*4096 + tid*16;
    int r = L>>7, cb = L&127;
    rr[s]=r; cc[s]=cb;
    if constexpr (GATHER){
      int m = m0 + r; int tt = m>>6, bb = m&63;
      srcA[s] = (const char*)(embB + (size_t)Xidx[bb*S_ + tt]*(size_t)K);
    } else {
      srcA[s] = (const char*)(Asrc + (size_t)(m0+r)*(size_t)K);
    }
    srcB[s] = (const char*)(Bw + (size_t)(n0+r)*(size_t)K);
  }

  f32x4 acc[4][4];
  #pragma unroll
  for (int a=0;a<4;a++)
    #pragma unroll
    for (int b=0;b<4;b++) acc[a][b] = (f32x4){0.f,0.f,0.f,0.f};

  int4 ra[4], rb[4];
  auto loadRegs = [&](int kt){
    #pragma unroll
    for (int s=0;s<4;s++){
      ra[s] = *(const int4*)(srcA[s] + (size_t)kt*128 + cc[s]);
      rb[s] = *(const int4*)(srcB[s] + (size_t)kt*128 + cc[s]);
    }
  };
  auto writeLDS = [&](){
    #pragma unroll
    for (int s=0;s<4;s++){
      int off = (rr[s]<<7) + (cc[s] ^ ((rr[s]&7)<<4));
      *(int4*)((char*)ldsA + off) = ra[s];
      *(int4*)((char*)ldsB + off) = rb[s];
    }
  };

  loadRegs(0);
  for (int kt=0; kt<KT; ++kt){
    __syncthreads();
    writeLDS();
    if (kt+1 < KT) loadRegs(kt+1);
    __syncthreads();
    #pragma unroll
    for (int ck=0; ck<2; ++ck){
      bf16x8 af[4], bfr[4];
      #pragma unroll
      for (int q=0;q<4;q++){
        int ar = wm + q*16 + (lane&15);
        int ao = (ar<<7) + (((ck<<6) + ((lane>>4)<<4)) ^ ((ar&7)<<4));
        af[q] = *(const bf16x8*)((const char*)ldsA + ao);
        int br = wn + q*16 + (lane&15);
        int bo = (br<<7) + (((ck<<6) + ((lane>>4)<<4)) ^ ((br&7)<<4));
        bfr[q] = *(const bf16x8*)((const char*)ldsB + bo);
      }
      #pragma unroll
      for (int mi=0;mi<4;mi++)
        #pragma unroll
        for (int ni=0;ni<4;ni++)
          acc[mi][ni] = __builtin_amdgcn_mfma_f32_16x16x32_bf16(af[mi], bfr[ni], acc[mi][ni], 0,0,0);
    }
  }

  #pragma unroll
  for (int mi=0;mi<4;mi++){
    #pragma unroll
    for (int ni=0;ni<4;ni++){
      int gm = m0 + wm + mi*16 + ((lane>>4)<<2);
      int gn = n0 + wn + ni*16 + (lane&15);
      float bv = bias[gn];
      #pragma unroll
      for (int r2=0;r2<4;r2++){
        float v = acc[mi][ni][r2] + bv;
        int m = gm + r2;
        if constexpr (SCATTER){
          ((float*)Cout)[ (size_t)((m&63)*S_ + (m>>6))*(size_t)ldc + gn ] = v;
        } else {
          ((unsigned short*)Cout)[ (size_t)m*(size_t)ldc + gn ] = f2bf(v);
        }
      }
    }
  }
}

// ---------------- persistent GRU scan (dataflow-flag sync) ----------------
DEV bf16x8 ld_frag_coh(const unsigned short* base, int row, int kk){
  const unsigned long long* p = (const unsigned long long*)(base + (size_t)row*H_ + kk);
  unsigned long long q0 = __hip_atomic_load(p,   __ATOMIC_RELAXED, __HIP_MEMORY_SCOPE_AGENT);
  unsigned long long q1 = __hip_atomic_load(p+1, __ATOMIC_RELAXED, __HIP_MEMORY_SCOPE_AGENT);
  union { unsigned long long q[2]; bf16x8 v; } u;
  u.q[0]=q0; u.q[1]=q1; return u.v;
}

// wave-0 vectorized poll: lane L checks flags 2L,2L+1 via one 8B coherent load
DEV void pollge(const unsigned int* f, unsigned int p, int lane){
  const unsigned long long* q = (const unsigned long long*)f;
  int guard = 0;
  for(;;){
    unsigned long long v = __hip_atomic_load(&q[lane], __ATOMIC_RELAXED, __HIP_MEMORY_SCOPE_AGENT);
    bool ok = ((unsigned)v >= p) && ((unsigned)(v>>32) >= p);
    if (__all((int)ok)) break;
    __builtin_amdgcn_s_sleep(2);
    if (++guard > (1<<22)) break;   // safety: garbage instead of hang
  }
}

__global__ __launch_bounds__(256) void k_scan(const float* __restrict__ h0, char* __restrict__ ws){
  const int wg = blockIdx.x;          // 0..127, owns H cols [wg*8, wg*8+8)
  const int tid = threadIdx.x;
  const int wave = tid>>6, lane = tid&63;
  const int j0 = wg*JS;

  unsigned int* fH = (unsigned int*)(ws + OFF_FH);
  unsigned int* fR = (unsigned int*)(ws + OFF_FR);
  unsigned short* hb  = (unsigned short*)(ws + OFF_HB);
  unsigned short* rhb = (unsigned short*)(ws + OFF_RHB);
  const unsigned short* G = (const unsigned short*)(ws + OFF_G);
  unsigned short* Hs  = (unsigned short*)(ws + OFF_HS);

  // stage weight fragments into LDS once (static across t)
  __shared__ char lds[65536];
  {
    const int4* s1 = (const int4*)(ws + OFF_WZRF + (size_t)wg*32768);
    const int4* s2 = (const int4*)(ws + OFF_WUF  + (size_t)wg*32768);
    int4* d = (int4*)lds;
    #pragma unroll
    for (int i=0;i<8;i++) d[tid + i*256]        = s1[tid + i*256];
    #pragma unroll
    for (int i=0;i<8;i++) d[2048 + tid + i*256] = s2[tid + i*256];
  }
  __syncthreads();
  const char* f1 = lds;
  const char* f2 = lds + 32768;

  const int n  = lane & 15;             // MFMA col
  const int c  = n & 7;                 // column within slice
  const bool isZ = (n < 8);
  const int rbase = (wave<<4) + ((lane>>4)<<2);   // D rows: batch base
  const int arow  = (wave<<4) + n;                // A rows: batch
  const int kkb   = (lane>>4)<<3;

  float h_own[4];                       // fp32 state, valid in isZ lanes
  #pragma unroll
  for (int r2=0;r2<4;r2++)
    h_own[r2] = isZ ? h0[(size_t)(rbase+r2)*H_ + j0 + c] : 0.f;

  for (int t=0; t<S_; ++t){
    // ---- prefetch gate offsets for this step (plain cached loads; hide under poll) ----
    const int gcol = ((n>>3)<<10) + j0 + c;   // z (n<8) / r (n>=8) column
    float g1[4], g2[4];
    #pragma unroll
    for (int r2=0;r2<4;r2++){
      g1[r2] = bf2f(G[(size_t)((t<<6)+rbase+r2)*3072 + gcol]);
      g2[r2] = isZ ? bf2f(G[(size_t)((t<<6)+rbase+r2)*3072 + 2048 + j0 + c]) : 0.f;
    }

    // ---- wait for h_t published by all WGs ----
    if (t > 0){
      if (wave == 0) pollge(fH, (unsigned)t, lane);
      __syncthreads();
    }

    // -------- stage 1: z,r = sigmoid(h@Wzr^T + G) --------
    f32x4 a0 = (f32x4){0,0,0,0}, a1 = (f32x4){0,0,0,0};
    #pragma unroll 4
    for (int ck=0; ck<32; ck+=2){
      bf16x8 av0 = ld_frag_coh(hb, arow, ck*32 + kkb);
      bf16x8 bv0 = *(const bf16x8*)(f1 + ((ck*64 + lane)<<4));
      a0 = __builtin_amdgcn_mfma_f32_16x16x32_bf16(av0, bv0, a0, 0,0,0);
      bf16x8 av1 = ld_frag_coh(hb, arow, (ck+1)*32 + kkb);
      bf16x8 bv1 = *(const bf16x8*)(f1 + (((ck+1)*64 + lane)<<4));
      a1 = __builtin_amdgcn_mfma_f32_16x16x32_bf16(av1, bv1, a1, 0,0,0);
    }
    f32x4 accs = a0 + a1;

    float zval[4];
    #pragma unroll
    for (int r2=0;r2<4;r2++){
      int brow = rbase + r2;
      float pre = accs[r2] + g1[r2];
      float sv = 1.f/(1.f + __expf(-pre));
      float hc = __shfl(h_own[r2], (lane & 48) | c, 64);
      zval[r2] = sv;
      if (!isZ){
        unsigned int mybits = (unsigned int)f2bf(sv*hc);
        unsigned int ob = __shfl_xor(mybits, 1, 64);
        if ((lane&1)==0){
          unsigned int w = mybits | (ob<<16);
          __hip_atomic_store((unsigned int*)(rhb + (size_t)brow*H_ + j0 + c), w,
                             __ATOMIC_RELAXED, __HIP_MEMORY_SCOPE_AGENT);
        }
      }
    }
    asm volatile("s_waitcnt vmcnt(0)" ::: "memory");
    __syncthreads();
    if (tid == 0)
      __hip_atomic_store(&fR[wg], (unsigned)(t+1), __ATOMIC_RELAXED, __HIP_MEMORY_SCOPE_AGENT);

    // ---- wait for rh published by all WGs ----
    if (wave == 0) pollge(fR, (unsigned)(t+1), lane);
    __syncthreads();

    // -------- stage 2: u = tanh((r*h)@Wu^T + G), h' = h + z*(u-h) --------
    f32x4 b0 = (f32x4){0,0,0,0}, b1 = (f32x4){0,0,0,0};
    #pragma unroll 4
    for (int ck=0; ck<32; ck+=2){
      bf16x8 av0 = ld_frag_coh(rhb, arow, ck*32 + kkb);
      bf16x8 bv0 = *(const bf16x8*)(f2 + ((ck*64 + lane)<<4));
      b0 = __builtin_amdgcn_mfma_f32_16x16x32_bf16(av0, bv0, b0, 0,0,0);
      bf16x8 av1 = ld_frag_coh(rhb, arow, (ck+1)*32 + kkb);
      bf16x8 bv1 = *(const bf16x8*)(f2 + (((ck+1)*64 + lane)<<4));
      b1 = __builtin_amdgcn_mfma_f32_16x16x32_bf16(av1, bv1, b1, 0,0,0);
    }
    f32x4 acc2 = b0 + b1;

    if (isZ){
      #pragma unroll
      for (int r2=0;r2<4;r2++){
        int brow = rbase + r2;
        float up = acc2[r2] + g2[r2];
        float e  = __expf(-2.f*up);
        float u  = (1.f - e)/(1.f + e);
        float hn = h_own[r2] + zval[r2]*(u - h_own[r2]);
        h_own[r2] = hn;
        unsigned int mybits = (unsigned int)f2bf(hn);
        unsigned int ob = __shfl_xor(mybits, 1, 64);
        if ((lane&1)==0){
          unsigned int w = mybits | (ob<<16);
          __hip_atomic_store((unsigned int*)(hb + (size_t)brow*H_ + j0 + c), w,
                             __ATOMIC_RELAXED, __HIP_MEMORY_SCOPE_AGENT);
          *(unsigned int*)(Hs + (size_t)((t<<6)+brow)*H_ + j0 + c) = w;   // plain store
        }
      }
    }
    asm volatile("s_waitcnt vmcnt(0)" ::: "memory");
    __syncthreads();
    if (tid == 0)
      __hip_atomic_store(&fH[wg], (unsigned)(t+1), __ATOMIC_RELAXED, __HIP_MEMORY_SCOPE_AGENT);
  }
}

// ---------------- launch ----------------
extern "C" void kernel_launch(void* const* d_in, const int* in_sizes, int n_in,
                              void* d_out, int out_size, void* d_ws, size_t ws_size,
                              hipStream_t stream)
{
  const int*   X    = (const int*)  d_in[0];
  const float* h0   = (const float*)d_in[1];
  const float* emb  = (const float*)d_in[2];
  const float* Wzh  = (const float*)d_in[3];
  const float* bzh  = (const float*)d_in[4];
  const float* Wzx  = (const float*)d_in[5];
  const float* bzx  = (const float*)d_in[6];
  const float* Wrh  = (const float*)d_in[7];
  const float* brh  = (const float*)d_in[8];
  const float* Wrx  = (const float*)d_in[9];
  const float* brx  = (const float*)d_in[10];
  const float* Wuh  = (const float*)d_in[11];
  const float* buh  = (const float*)d_in[12];
  const float* Wux  = (const float*)d_in[13];
  const float* bux  = (const float*)d_in[14];
  const float* Wxh  = (const float*)d_in[15];
  const float* bxh  = (const float*)d_in[16];
  const float* Wc   = (const float*)d_in[17];
  const float* bc   = (const float*)d_in[18];
  (void)in_sizes; (void)n_in;

  char* ws = (char*)d_ws;
  if (ws_size < WS_NEED){
    hipMemsetAsync(d_out, 0, (size_t)out_size*4, stream);  // visible failure
    return;
  }

  hipMemsetAsync(ws + OFF_FH, 0, 1024, stream);   // fH + fR

  k_cvt_embed<<<4096, 256, 0, stream>>>(emb, (unsigned short*)(ws + OFF_EMB));
  k_build_wx <<<1536, 256, 0, stream>>>(Wzx, Wrx, Wux, (unsigned short*)(ws + OFF_WXALL));
  k_biasg    <<<12,   256, 0, stream>>>(bzh, bzx, brh, brx, buh, bux, (float*)(ws + OFF_BIASG));
  k_frag     <<<2048, 256, 0, stream>>>(Wzh, Wrh,    (unsigned short*)(ws + OFF_WZRF));
  k_frag     <<<2048, 256, 0, stream>>>(Wuh, nullptr,(unsigned short*)(ws + OFF_WUF));
  k_wcomb    <<<64,   256, 0, stream>>>(Wc, Wxh, (unsigned short*)(ws + OFF_WCOMB));
  k_bcomb    <<<4,    256, 0, stream>>>(Wc, bxh, bc, (float*)(ws + OFF_BCOMB));
  k_hinit    <<<64,   256, 0, stream>>>(h0, (unsigned short*)(ws + OFF_HB));

  // G = gather(embed) @ WxAll^T + bias  -> [S*B rows (t-major), 3072] bf16
  gemm_bt<true,false><<<6144, 256, 0, stream>>>(
      nullptr, X, (const unsigned short*)(ws + OFF_EMB),
      (const unsigned short*)(ws + OFF_WXALL), (const float*)(ws + OFF_BIASG),
      (void*)(ws + OFF_G), 512, 8, 24, 3072);

  k_scan<<<NWG, 256, 0, stream>>>(h0, ws);

  // out[b,t,c] = Hs @ Wcomb^T + bcomb (scatter rows t*64+b -> b*512+t)
  gemm_bt<false,true><<<2048, 256, 0, stream>>>(
      (const unsigned short*)(ws + OFF_HS), nullptr, nullptr,
      (const unsigned short*)(ws + OFF_WCOMB), (const float*)(ws + OFF_BCOMB),
      d_out, 1024, 16, 8, 1024);
}

// Round 3
// 6753.764 us; speedup vs baseline: 2.6284x; 1.8281x over previous
//
#include <hip/hip_runtime.h>

#define DEV __device__ __forceinline__

using bf16x8 = __attribute__((ext_vector_type(8))) short;
using u16x4  = __attribute__((ext_vector_type(4))) unsigned short;
using f32x4  = __attribute__((ext_vector_type(4))) float;

constexpr int B_ = 64, S_ = 512, V_ = 32000, E_ = 512, H_ = 1024, C_ = 1024;
constexpr int NWG = 128;   // scan workgroups (each owns JS columns of H)
constexpr int JS  = 8;

// ---------------- workspace layout (bytes) ----------------
constexpr size_t OFF_FH    = 0;                                   // 128 u32 h-ready flags
constexpr size_t OFF_FR    = 512;                                 // 128 u32 rh-ready flags
constexpr size_t OFF_BIASG = 1024;                                // 3072 f32
constexpr size_t OFF_BCOMB = OFF_BIASG + 3072*4;                  // 1024 f32
constexpr size_t OFF_HB    = OFF_BCOMB + 1024*4;                  // hF frag-layout bf16 [64][1024]
constexpr size_t OFF_RHB   = OFF_HB + (size_t)B_*H_*2;            // rhF frag-layout bf16
constexpr size_t OFF_WCOMB = OFF_RHB + (size_t)B_*H_*2;           // [1024][1024] bf16
constexpr size_t OFF_WXALL = OFF_WCOMB + (size_t)C_*H_*2;         // [3072][512] bf16
constexpr size_t OFF_WZRF  = OFF_WXALL + (size_t)3072*512*2;      // stage1 frags 128*32KB
constexpr size_t OFF_WUF   = OFF_WZRF + (size_t)NWG*32768;        // stage2 packed frags 128*16KB
constexpr size_t OFF_EMB   = OFF_WUF + (size_t)NWG*16384;         // embed bf16 [32000][512]
constexpr size_t OFF_G     = OFF_EMB + (size_t)V_*E_*2;           // [512][3072][64] bf16
constexpr size_t OFF_HS    = OFF_G + (size_t)S_*B_*3072*2;        // [512*64][1024] bf16
constexpr size_t WS_NEED   = OFF_HS + (size_t)S_*B_*H_*2;         // ~299 MiB

DEV unsigned short f2bf(float f){
  unsigned int x; __builtin_memcpy(&x, &f, 4);
  x += 0x7fffu + ((x>>16)&1u);
  return (unsigned short)(x>>16);
}
DEV float bf2f(unsigned short u){
  unsigned int x = ((unsigned int)u)<<16; float f; __builtin_memcpy(&f,&x,4); return f;
}

// coherent (MALL) 16B load/store + plain 8B load, all volatile asm so the
// hand-counted vmcnt() regions see no compiler-scheduled VMEM.
DEV int4 ld16_coh(const char* p){
  int4 r;
  asm volatile("global_load_dwordx4 %0, %1, off sc0 sc1" : "=v"(r) : "v"(p) : "memory");
  return r;
}
DEV void st16_coh(char* p, bf16x8 v){
  asm volatile("global_store_dwordx4 %0, %1, off sc0 sc1" :: "v"(p), "v"(v) : "memory");
}
DEV uint2 ld8_plain(const char* p){
  uint2 r;
  asm volatile("global_load_dwordx2 %0, %1, off" : "=v"(r) : "v"(p) : "memory");
  return r;
}

#define WAITVM(N) do{ asm volatile("s_waitcnt vmcnt(" #N ")" ::: "memory"); \
                      __builtin_amdgcn_sched_barrier(0); }while(0)

// ---------------- prep kernels ----------------
__global__ void k_cvt_embed(const float* __restrict__ src, unsigned short* __restrict__ dst){
  for (int i = blockIdx.x*blockDim.x + threadIdx.x; i < V_*E_; i += gridDim.x*blockDim.x)
    dst[i] = f2bf(src[i]);
}

__global__ void k_build_wx(const float* __restrict__ Wzx, const float* __restrict__ Wrx,
                           const float* __restrict__ Wux, unsigned short* __restrict__ out){
  for (int i = blockIdx.x*blockDim.x + threadIdx.x; i < 3072*512; i += gridDim.x*blockDim.x){
    int n = i>>9, k = i&511;
    int g = n>>10, r = n&1023;
    const float* W = (g==0) ? Wzx : (g==1) ? Wrx : Wux;
    out[i] = f2bf(W[(size_t)r*512 + k]);
  }
}

__global__ void k_biasg(const float* bzh, const float* bzx, const float* brh, const float* brx,
                        const float* buh, const float* bux, float* __restrict__ out){
  for (int i = blockIdx.x*blockDim.x + threadIdx.x; i < 3072; i += gridDim.x*blockDim.x){
    int g = i>>10, r = i&1023;
    float v = (g==0) ? (bzh[r]+bzx[r]) : (g==1) ? (brh[r]+brx[r]) : (buh[r]+bux[r]);
    out[i] = v;
  }
}

// stage1 B-frags: frag[((wg*32+ck)*64+l)*8+e] = W[row][k], col=l&15 (z:0-7 -> Wzh, r:8-15 -> Wrh)
__global__ void k_frag(const float* __restrict__ Wa, const float* __restrict__ Wb,
                       unsigned short* __restrict__ out){
  for (int i = blockIdx.x*blockDim.x + threadIdx.x; i < NWG*32*64*8; i += gridDim.x*blockDim.x){
    int e  = i & 7;
    int l  = (i>>3) & 63;
    int ck = (i>>9) & 31;
    int wg = i>>14;
    int j  = l & 15;
    int k  = ck*32 + ((l>>4)<<3) + e;
    int row = wg*JS + (j&7);
    float v = (j < 8) ? Wa[(size_t)row*H_ + k] : Wb[(size_t)row*H_ + k];
    out[i] = f2bf(v);
  }
}

// stage2 packed frags (only cols 0..7 used): out[((wg*32+ck)*32+p)*8+e],
// p = h8*8+nn -> Wuh[wg*8+nn][ck*32+h8*8+e]
__global__ void k_frag2(const float* __restrict__ Wuh, unsigned short* __restrict__ out){
  for (int i = blockIdx.x*blockDim.x + threadIdx.x; i < NWG*32*32*8; i += gridDim.x*blockDim.x){
    int e=i&7, p=(i>>3)&31, ck=(i>>8)&31, wg=i>>13;
    int nn=p&7, h8=p>>3;
    out[i] = f2bf(Wuh[(size_t)(wg*8+nn)*H_ + ck*32 + h8*8 + e]);
  }
}

// Wcomb[c][h] = sum_x Wc[c][x] * Wxh[x][h]
__global__ __launch_bounds__(256) void k_wcomb(const float* __restrict__ Wc,
                                               const float* __restrict__ Wxh,
                                               unsigned short* __restrict__ Wcomb){
  __shared__ float wc[16][512];
  const int c0 = blockIdx.x*16;
  const int tid = threadIdx.x;
  for (int q = tid; q < 16*512; q += 256)
    wc[q>>9][q&511] = Wc[(size_t)(c0 + (q>>9))*512 + (q&511)];
  __syncthreads();
  const int h4 = tid*4;
  f32x4 acc[16];
  #pragma unroll
  for (int ci=0; ci<16; ++ci) acc[ci] = (f32x4){0.f,0.f,0.f,0.f};
  for (int x=0; x<512; ++x){
    f32x4 wv = *(const f32x4*)(Wxh + (size_t)x*H_ + h4);
    #pragma unroll
    for (int ci=0; ci<16; ++ci) acc[ci] += wc[ci][x] * wv;
  }
  #pragma unroll
  for (int ci=0; ci<16; ++ci)
    #pragma unroll
    for (int e=0; e<4; ++e)
      Wcomb[(size_t)(c0+ci)*H_ + h4 + e] = f2bf(acc[ci][e]);
}

__global__ void k_bcomb(const float* __restrict__ Wc, const float* __restrict__ bxh,
                        const float* __restrict__ bc, float* __restrict__ out){
  int c = blockIdx.x*blockDim.x + threadIdx.x;
  if (c >= C_) return;
  float s = bc[c];
  for (int x=0; x<512; ++x) s += Wc[(size_t)c*512 + x]*bxh[x];
  out[c] = s;
}

// h0 -> fragment layout
__global__ void k_hinit(const float* __restrict__ h0, unsigned short* __restrict__ hbF){
  int i = blockIdx.x*256 + threadIdx.x;   // 65536 total
  int e=i&7, l=(i>>3)&63, ck=(i>>9)&31, w=i>>14;
  hbF[i] = f2bf(h0[(size_t)(w*16+(l&15))*H_ + ck*32 + ((l>>4)<<3) + e]);
}

// ---------------- tiled bf16 MFMA GEMM (C = A @ Bw^T + bias) ----------------
// MODE 1: f32 out scattered to [b][t][C]; MODE 2: bf16 out to G layout [t][gcol][64b]
template<bool GATHER, int MODE>
__global__ __launch_bounds__(256) void gemm_bt(
  const unsigned short* __restrict__ Asrc, const int* __restrict__ Xidx,
  const unsigned short* __restrict__ embB,
  const unsigned short* __restrict__ Bw, const float* __restrict__ bias,
  void* __restrict__ Cout, int K, int KT, int NTN, int ldc)
{
  __shared__ unsigned short ldsA[128*64];
  __shared__ unsigned short ldsB[128*64];
  const int bid = blockIdx.x;
  const int tm = bid / NTN, tn = bid % NTN;
  const int m0 = tm*128, n0 = tn*128;
  const int tid = threadIdx.x, wave = tid>>6, lane = tid&63;
  const int wm = (wave&1)*64, wn = (wave>>1)*64;

  const char* srcA[4]; const char* srcB[4];
  int rr[4], cc[4];
  #pragma unroll
  for (int s=0; s<4; ++s){
    int L = s*4096 + tid*16;
    int r = L>>7, cb = L&127;
    rr[s]=r; cc[s]=cb;
    if constexpr (GATHER){
      int m = m0 + r; int tt = m>>6, bb = m&63;
      srcA[s] = (const char*)(embB + (size_t)Xidx[bb*S_ + tt]*(size_t)K);
    } else {
      srcA[s] = (const char*)(Asrc + (size_t)(m0+r)*(size_t)K);
    }
    srcB[s] = (const char*)(Bw + (size_t)(n0+r)*(size_t)K);
  }

  f32x4 acc[4][4];
  #pragma unroll
  for (int a=0;a<4;a++)
    #pragma unroll
    for (int b=0;b<4;b++) acc[a][b] = (f32x4){0.f,0.f,0.f,0.f};

  int4 ra[4], rb[4];
  auto loadRegs = [&](int kt){
    #pragma unroll
    for (int s=0;s<4;s++){
      ra[s] = *(const int4*)(srcA[s] + (size_t)kt*128 + cc[s]);
      rb[s] = *(const int4*)(srcB[s] + (size_t)kt*128 + cc[s]);
    }
  };
  auto writeLDS = [&](){
    #pragma unroll
    for (int s=0;s<4;s++){
      int off = (rr[s]<<7) + (cc[s] ^ ((rr[s]&7)<<4));
      *(int4*)((char*)ldsA + off) = ra[s];
      *(int4*)((char*)ldsB + off) = rb[s];
    }
  };

  loadRegs(0);
  for (int kt=0; kt<KT; ++kt){
    __syncthreads();
    writeLDS();
    if (kt+1 < KT) loadRegs(kt+1);
    __syncthreads();
    #pragma unroll
    for (int ck=0; ck<2; ++ck){
      bf16x8 af[4], bfr[4];
      #pragma unroll
      for (int q=0;q<4;q++){
        int ar = wm + q*16 + (lane&15);
        int ao = (ar<<7) + (((ck<<6) + ((lane>>4)<<4)) ^ ((ar&7)<<4));
        af[q] = *(const bf16x8*)((const char*)ldsA + ao);
        int br = wn + q*16 + (lane&15);
        int bo = (br<<7) + (((ck<<6) + ((lane>>4)<<4)) ^ ((br&7)<<4));
        bfr[q] = *(const bf16x8*)((const char*)ldsB + bo);
      }
      #pragma unroll
      for (int mi=0;mi<4;mi++)
        #pragma unroll
        for (int ni=0;ni<4;ni++)
          acc[mi][ni] = __builtin_amdgcn_mfma_f32_16x16x32_bf16(af[mi], bfr[ni], acc[mi][ni], 0,0,0);
    }
  }

  #pragma unroll
  for (int mi=0;mi<4;mi++){
    #pragma unroll
    for (int ni=0;ni<4;ni++){
      int gm = m0 + wm + mi*16 + ((lane>>4)<<2);
      int gn = n0 + wn + ni*16 + (lane&15);
      float bv = bias[gn];
      if constexpr (MODE == 1){
        #pragma unroll
        for (int r2=0;r2<4;r2++){
          float v = acc[mi][ni][r2] + bv;
          int m = gm + r2;
          ((float*)Cout)[ (size_t)((m&63)*S_ + (m>>6))*(size_t)ldc + gn ] = v;
        }
      } else {
        int t0 = gm>>6, b0 = gm&63;
        u16x4 pk;
        #pragma unroll
        for (int r2=0;r2<4;r2++) pk[r2] = f2bf(acc[mi][ni][r2] + bv);
        *(u16x4*)((unsigned short*)Cout + ((size_t)t0*3072 + gn)*64 + b0) = pk;
      }
    }
  }
}

// ---------------- persistent GRU scan ----------------
DEV void pollge(const unsigned int* f, unsigned int p, int lane){
  const unsigned long long* q = (const unsigned long long*)f;
  int guard = 0;
  for(;;){
    unsigned long long v = __hip_atomic_load(&q[lane], __ATOMIC_RELAXED, __HIP_MEMORY_SCOPE_AGENT);
    bool ok = ((unsigned)v >= p) && ((unsigned)(v>>32) >= p);
    if (__all((int)ok)) break;
    __builtin_amdgcn_s_sleep(1);
    if (++guard > (1<<22)) break;   // safety: garbage instead of hang
  }
}

__global__ __launch_bounds__(256) void k_scan(const float* __restrict__ h0, char* __restrict__ ws){
  const int wg = blockIdx.x;          // owns H cols [wg*8, wg*8+8)
  const int tid = threadIdx.x;
  const int wave = tid>>6, lane = tid&63;
  const int j0 = wg*JS;
  const int ckw = wg>>2, hiw = wg&3;

  unsigned int* fH = (unsigned int*)(ws + OFF_FH);
  unsigned int* fR = (unsigned int*)(ws + OFF_FR);
  char* hbF  = ws + OFF_HB;
  char* rhbF = ws + OFF_RHB;
  const unsigned short* G = (const unsigned short*)(ws + OFF_G);
  unsigned short* Hs  = (unsigned short*)(ws + OFF_HS);

  __shared__ __align__(16) char lds[32768 + 16384 + 1024 + 1024];
  char* f1  = lds;
  char* f2p = lds + 32768;
  unsigned short* tileA = (unsigned short*)(lds + 49152);  // rh shuffle [64][8]
  unsigned short* tileB = (unsigned short*)(lds + 50176);  // h' shuffle [64][8]

  { // stage static weight fragments into LDS
    const int4* s1 = (const int4*)(ws + OFF_WZRF + (size_t)wg*32768);
    const int4* s2 = (const int4*)(ws + OFF_WUF  + (size_t)wg*16384);
    #pragma unroll
    for (int i=0;i<8;i++) ((int4*)f1)[tid + i*256] = s1[tid + i*256];
    #pragma unroll
    for (int i=0;i<4;i++) ((int4*)f2p)[tid + i*256] = s2[tid + i*256];
  }
  __syncthreads();

  const int n  = lane & 15;
  const int c  = n & 7;
  const bool isZ = (n < 8);
  const int hi2 = lane>>4;
  const int rbase = (wave<<4) + (hi2<<2);
  const int gcol = ((n>>3)<<10) + j0 + c;   // z col (n<8) / r col (n>=8)
  const int col2 = 2048 + j0 + c;           // u col

  float h_own[4];
  #pragma unroll
  for (int r2=0;r2<4;r2++)
    h_own[r2] = isZ ? h0[(size_t)(rbase+r2)*H_ + j0 + c] : 0.f;

  const char* myHb  = hbF  + ((size_t)wave<<15);   // wave's 32KB block row-group
  const char* myRhb = rhbF + ((size_t)wave<<15);

#define LOAD8(buf, base, g0) { _Pragma("unroll") \
  for (int i=0;i<8;i++) buf[i] = ld16_coh((base) + ((((g0)*8+i)*64+lane)<<4)); }
#define MFMA8_1(buf, g0) { _Pragma("unroll") \
  for (int i=0;i<8;i++){ int ck=(g0)*8+i; \
    bf16x8 bv = *(const bf16x8*)(f1 + ((ck*64+lane)<<4)); \
    bf16x8 av = __builtin_bit_cast(bf16x8, buf[i]); \
    if (i&1) acc1 = __builtin_amdgcn_mfma_f32_16x16x32_bf16(av,bv,acc1,0,0,0); \
    else     acc0 = __builtin_amdgcn_mfma_f32_16x16x32_bf16(av,bv,acc0,0,0,0);} }
#define MFMA8_2(buf, g0) { _Pragma("unroll") \
  for (int i=0;i<8;i++){ int ck=(g0)*8+i; \
    bf16x8 bv = *(const bf16x8*)(f2p + ((ck*32 + hi2*8 + c)<<4)); \
    bf16x8 av = __builtin_bit_cast(bf16x8, buf[i]); \
    if (i&1) acc1 = __builtin_amdgcn_mfma_f32_16x16x32_bf16(av,bv,acc1,0,0,0); \
    else     acc0 = __builtin_amdgcn_mfma_f32_16x16x32_bf16(av,bv,acc0,0,0,0);} }

  for (int t=0; t<S_; ++t){
    // G prefetch (plain cached, coalesced 8B/lane); latency hides under poll
    uint2 gv1 = ld8_plain((const char*)(G + ((size_t)t*3072 + gcol)*64 + rbase));
    uint2 gv2 = ld8_plain((const char*)(G + ((size_t)t*3072 + col2)*64 + rbase));

    if (t > 0) pollge(fH, (unsigned)t, lane);
    WAITVM(0);

    // -------- stage 1: z,r = sigmoid(h@Wzr^T + G) --------
    f32x4 acc0 = (f32x4){0,0,0,0}, acc1 = (f32x4){0,0,0,0};
    {
      int4 bufA[8], bufB[8];
      LOAD8(bufA, myHb, 0);
      LOAD8(bufB, myHb, 1); WAITVM(8); MFMA8_1(bufA, 0);
      LOAD8(bufA, myHb, 2); WAITVM(8); MFMA8_1(bufB, 1);
      LOAD8(bufB, myHb, 3); WAITVM(8); MFMA8_1(bufA, 2);
      WAITVM(0);            MFMA8_1(bufB, 3);
    }
    f32x4 accs = acc0 + acc1;

    float zval[4];
    {
      unsigned short gu[4] = {(unsigned short)(gv1.x&0xffffu),(unsigned short)(gv1.x>>16),
                              (unsigned short)(gv1.y&0xffffu),(unsigned short)(gv1.y>>16)};
      #pragma unroll
      for (int r2=0;r2<4;r2++){
        float pre = accs[r2] + bf2f(gu[r2]);
        float sv = 1.f/(1.f + __expf(-pre));
        float hc = __shfl(h_own[r2], (lane & 48) | c, 64);
        zval[r2] = sv;
        if (!isZ) tileA[(wave*16 + hi2*4 + r2)*8 + c] = f2bf(sv*hc);
      }
    }
    __syncthreads();
    if (wave == 0){
      bf16x8 v = *(const bf16x8*)(tileA + lane*8);
      st16_coh(rhbF + ((((lane>>4)*32 + ckw)<<10) + (hiw<<8) + ((lane&15)<<4)), v);
      asm volatile("s_waitcnt vmcnt(0)" ::: "memory");
      if (lane == 0)
        __hip_atomic_store(&fR[wg], (unsigned)(t+1), __ATOMIC_RELAXED, __HIP_MEMORY_SCOPE_AGENT);
    }
    pollge(fR, (unsigned)(t+1), lane);
    WAITVM(0);

    // -------- stage 2: u = tanh((r*h)@Wu^T + G), h' = h + z*(u-h) --------
    acc0 = (f32x4){0,0,0,0}; acc1 = (f32x4){0,0,0,0};
    {
      int4 bufA[8], bufB[8];
      LOAD8(bufA, myRhb, 0);
      LOAD8(bufB, myRhb, 1); WAITVM(8); MFMA8_2(bufA, 0);
      LOAD8(bufA, myRhb, 2); WAITVM(8); MFMA8_2(bufB, 1);
      LOAD8(bufB, myRhb, 3); WAITVM(8); MFMA8_2(bufA, 2);
      WAITVM(0);             MFMA8_2(bufB, 3);
    }
    f32x4 acc2 = acc0 + acc1;

    if (isZ){
      unsigned short gu[4] = {(unsigned short)(gv2.x&0xffffu),(unsigned short)(gv2.x>>16),
                              (unsigned short)(gv2.y&0xffffu),(unsigned short)(gv2.y>>16)};
      #pragma unroll
      for (int r2=0;r2<4;r2++){
        float up = acc2[r2] + bf2f(gu[r2]);
        float e  = __expf(-2.f*up);
        float u  = (1.f - e)/(1.f + e);
        float hn = h_own[r2] + zval[r2]*(u - h_own[r2]);
        h_own[r2] = hn;
        tileB[(wave*16 + hi2*4 + r2)*8 + c] = f2bf(hn);
      }
    }
    __syncthreads();
    if (wave == 0){
      bf16x8 v = *(const bf16x8*)(tileB + lane*8);
      st16_coh(hbF + ((((lane>>4)*32 + ckw)<<10) + (hiw<<8) + ((lane&15)<<4)), v);
      *(bf16x8*)(Hs + (size_t)((t<<6) + lane)*H_ + j0) = v;   // history, plain store
      asm volatile("s_waitcnt vmcnt(0)" ::: "memory");
      if (lane == 0)
        __hip_atomic_store(&fH[wg], (unsigned)(t+1), __ATOMIC_RELAXED, __HIP_MEMORY_SCOPE_AGENT);
    }
  }
#undef LOAD8
#undef MFMA8_1
#undef MFMA8_2
}

// ---------------- launch ----------------
extern "C" void kernel_launch(void* const* d_in, const int* in_sizes, int n_in,
                              void* d_out, int out_size, void* d_ws, size_t ws_size,
                              hipStream_t stream)
{
  const int*   X    = (const int*)  d_in[0];
  const float* h0   = (const float*)d_in[1];
  const float* emb  = (const float*)d_in[2];
  const float* Wzh  = (const float*)d_in[3];
  const float* bzh  = (const float*)d_in[4];
  const float* Wzx  = (const float*)d_in[5];
  const float* bzx  = (const float*)d_in[6];
  const float* Wrh  = (const float*)d_in[7];
  const float* brh  = (const float*)d_in[8];
  const float* Wrx  = (const float*)d_in[9];
  const float* brx  = (const float*)d_in[10];
  const float* Wuh  = (const float*)d_in[11];
  const float* buh  = (const float*)d_in[12];
  const float* Wux  = (const float*)d_in[13];
  const float* bux  = (const float*)d_in[14];
  const float* Wxh  = (const float*)d_in[15];
  const float* bxh  = (const float*)d_in[16];
  const float* Wc   = (const float*)d_in[17];
  const float* bc   = (const float*)d_in[18];
  (void)in_sizes; (void)n_in;

  char* ws = (char*)d_ws;
  if (ws_size < WS_NEED){
    hipMemsetAsync(d_out, 0, (size_t)out_size*4, stream);  // visible failure
    return;
  }

  hipMemsetAsync(ws + OFF_FH, 0, 1024, stream);   // fH + fR

  k_cvt_embed<<<4096, 256, 0, stream>>>(emb, (unsigned short*)(ws + OFF_EMB));
  k_build_wx <<<1536, 256, 0, stream>>>(Wzx, Wrx, Wux, (unsigned short*)(ws + OFF_WXALL));
  k_biasg    <<<12,   256, 0, stream>>>(bzh, bzx, brh, brx, buh, bux, (float*)(ws + OFF_BIASG));
  k_frag     <<<2048, 256, 0, stream>>>(Wzh, Wrh, (unsigned short*)(ws + OFF_WZRF));
  k_frag2    <<<1024, 256, 0, stream>>>(Wuh,      (unsigned short*)(ws + OFF_WUF));
  k_wcomb    <<<64,   256, 0, stream>>>(Wc, Wxh, (unsigned short*)(ws + OFF_WCOMB));
  k_bcomb    <<<4,    256, 0, stream>>>(Wc, bxh, bc, (float*)(ws + OFF_BCOMB));
  k_hinit    <<<256,  256, 0, stream>>>(h0, (unsigned short*)(ws + OFF_HB));

  // G = gather(embed) @ WxAll^T + bias -> layout [t][gcol][64b] bf16
  gemm_bt<true,2><<<6144, 256, 0, stream>>>(
      nullptr, X, (const unsigned short*)(ws + OFF_EMB),
      (const unsigned short*)(ws + OFF_WXALL), (const float*)(ws + OFF_BIASG),
      (void*)(ws + OFF_G), 512, 8, 24, 3072);

  k_scan<<<NWG, 256, 0, stream>>>(h0, ws);

  // out[b,t,c] = Hs @ Wcomb^T + bcomb (scatter rows t*64+b -> b*512+t)
  gemm_bt<false,1><<<2048, 256, 0, stream>>>(
      (const unsigned short*)(ws + OFF_HS), nullptr, nullptr,
      (const unsigned short*)(ws + OFF_WCOMB), (const float*)(ws + OFF_BCOMB),
      d_out, 1024, 16, 8, 1024);
}